// Round 11
// baseline (120.910 us; speedup 1.0000x reference)
//
#include <hip/hip_runtime.h>
#include <math.h>

#define F_DIM 256
#define D_DIM 128
#define LEAKY 0.2f

using bf16x8 = __attribute__((ext_vector_type(8))) short;
using f32x4  = __attribute__((ext_vector_type(4))) float;
using u32x4  = __attribute__((ext_vector_type(4))) unsigned;

__device__ __forceinline__ float wave_sum(float v) {
#pragma unroll
  for (int o = 32; o; o >>= 1) v += __shfl_xor(v, o);
  return v;
}
// fp32 -> bf16 round-to-nearest-even (bit-exact RNE)
__device__ __forceinline__ unsigned short f2bf(float f) {
  unsigned u = __float_as_uint(f);
  u += 0x7fffu + ((u >> 16) & 1u);
  return (unsigned short)(u >> 16);
}
__device__ __forceinline__ unsigned cvt2(float lo, float hi) {
  return (unsigned)f2bf(lo) | ((unsigned)f2bf(hi) << 16);
}

// Fused prep: block 0 -> u1/u2 = Wmap^T {w1,w2}; blocks 1..128 -> kTb
// transpose (one d-row each); blocks 129+ -> row_ptr binary search.
__global__ __launch_bounds__(256) void prep_kernel(
    const float* __restrict__ Wmap, const float* __restrict__ w1,
    const float* __restrict__ w2, float* __restrict__ u,
    const float* __restrict__ kern, unsigned short* __restrict__ kTb,
    const int* __restrict__ edge_row, int* __restrict__ row_ptr,
    int N, int E) {
  int bid = blockIdx.x;
  int t = threadIdx.x;
  if (bid == 0) {
    __shared__ float w1s[D_DIM], w2s[D_DIM];
    if (t < D_DIM) { w1s[t] = w1[t]; w2s[t] = w2[t]; }
    __syncthreads();
    float a1 = 0.f, a2 = 0.f;
    const float* wp = Wmap + (size_t)t * D_DIM;
#pragma unroll 8
    for (int d = 0; d < D_DIM; ++d) {
      float wv = wp[d];
      a1 += wv * w1s[d];
      a2 += wv * w2s[d];
    }
    u[t] = a1;
    u[F_DIM + t] = a2;
  } else if (bid <= D_DIM) {
    int d = bid - 1;        // 0..127
    int k = t;              // 0..255
    kTb[d * F_DIM + k] = f2bf(kern[(size_t)k * D_DIM + d]);
  } else {
    int r = (bid - D_DIM - 1) * 256 + t;
    if (r > N) return;
    int lo = 0, hi = E;
    while (lo < hi) {
      int mid = (lo + hi) >> 1;
      if (edge_row[mid] < r) lo = mid + 1; else hi = mid;
    }
    row_ptr[r] = lo;
  }
}

// Fused: value = bf16(x @ kernel) via MFMA (row-major [N][128]) +
// sa1/sa2 = x·u + b. Block = 8 waves / 128 rows (512 threads): 64 KB LDS
// -> 2 blocks/CU = 16 waves/CU, and kTb staged once per 128 rows (halves
// the L2-side staging traffic vs 64-row blocks). XOR-swizzled LDS
// (write & read use the same involution). A-frag lane l: row (l&15),
// kg=(l>>4). C/D: col = l&15, row = (l>>4)*4 + i  [guide §3, m89-verified]
__global__ __launch_bounds__(512) void value_sa_gemm_kernel(
    const float* __restrict__ x, const unsigned short* __restrict__ kTb,
    const float* __restrict__ u, const float* __restrict__ b1,
    const float* __restrict__ b2, unsigned short* __restrict__ value,
    float* __restrict__ sa1, float* __restrict__ sa2, int N) {
  __shared__ unsigned short ldsb[F_DIM * D_DIM];  // 64 KB exactly
  int tid = threadIdx.x;
  int w = tid >> 6, l = tid & 63;
  int rl = l & 15, kg = l >> 4;
  int row = blockIdx.x * 128 + w * 16 + rl;
  bool valid = row < N;
  int rowc = valid ? row : N - 1;

  // ---- staging loads: whole 64 KB kTb, 512 threads x 8 x 16B ----
  bf16x8 stg[8];
#pragma unroll
  for (int it = 0; it < 8; ++it)
    stg[it] = *(const bf16x8*)(kTb + (size_t)(tid + it * 512) * 8);

  const float* xp = x + (size_t)rowc * F_DIM + kg * 8;
  float4 fxa[8], fxb[8];
#pragma unroll
  for (int ks = 0; ks < 8; ++ks) {
    fxa[ks] = *(const float4*)(xp + ks * 32);
    fxb[ks] = *(const float4*)(xp + ks * 32 + 4);
  }

  // ---- swizzled LDS writes: chunk c -> byte d*512 + ((slot*16)^((d&7)<<4))
#pragma unroll
  for (int it = 0; it < 8; ++it) {
    int c = tid + it * 512;
    int d = c >> 5;
    int sw = d * 512 + (((c & 31) * 16) ^ ((d & 7) << 4));
    *(bf16x8*)((char*)ldsb + sw) = stg[it];
  }

  const float* u1p = u + kg * 8;
  const float* u2p = u + F_DIM + kg * 8;
  float d1 = 0.f, d2 = 0.f;
  bf16x8 af[8];
#pragma unroll
  for (int ks = 0; ks < 8; ++ks) {
    float4 fa = fxa[ks], fb = fxb[ks];
    float4 ua = *(const float4*)(u1p + ks * 32);
    float4 ub = *(const float4*)(u1p + ks * 32 + 4);
    d1 += fa.x * ua.x + fa.y * ua.y + fa.z * ua.z + fa.w * ua.w +
          fb.x * ub.x + fb.y * ub.y + fb.z * ub.z + fb.w * ub.w;
    float4 va = *(const float4*)(u2p + ks * 32);
    float4 vb = *(const float4*)(u2p + ks * 32 + 4);
    d2 += fa.x * va.x + fa.y * va.y + fa.z * va.z + fa.w * va.w +
          fb.x * vb.x + fb.y * vb.y + fb.z * vb.z + fb.w * vb.w;
    u32x4 p;
    p[0] = cvt2(fa.x, fa.y);
    p[1] = cvt2(fa.z, fa.w);
    p[2] = cvt2(fb.x, fb.y);
    p[3] = cvt2(fb.z, fb.w);
    af[ks] = __builtin_bit_cast(bf16x8, p);
  }
  __syncthreads();

  f32x4 acc[8];
#pragma unroll
  for (int n = 0; n < 8; ++n) acc[n] = (f32x4){0.f, 0.f, 0.f, 0.f};
#pragma unroll
  for (int ks = 0; ks < 8; ++ks) {
    int bir = (ks * 64 + kg * 16) ^ ((rl & 7) << 4);
    const char* bp = (const char*)ldsb + rl * 512 + bir;
#pragma unroll
    for (int n = 0; n < 8; ++n) {
      bf16x8 b = *(const bf16x8*)(bp + n * 8192);
      acc[n] = __builtin_amdgcn_mfma_f32_16x16x32_bf16(af[ks], b, acc[n], 0, 0, 0);
    }
  }

  d1 += __shfl_xor(d1, 16); d1 += __shfl_xor(d1, 32);
  d2 += __shfl_xor(d2, 16); d2 += __shfl_xor(d2, 32);
  if (valid && kg == 0) {
    sa1[row] = d1 + b1[0];
    sa2[row] = d2 + b2[0];
  }
  int orow0 = blockIdx.x * 128 + w * 16 + kg * 4;
#pragma unroll
  for (int n = 0; n < 8; ++n) {
#pragma unroll
    for (int i = 0; i < 4; ++i) {
      int gr = orow0 + i;
      if (gr < N) value[(size_t)gr * D_DIM + n * 16 + rl] = f2bf(acc[n][i]);
    }
  }
}

// One wave per row, single pass, fixed softmax max = 0 (scores hard-bounded
// small by Cauchy-Schwarz; exp cannot overflow — identical to max-sub
// softmax). Per 64-edge chunk: lanes compute p=exp(sc) in parallel, stash
// (p, col) in LDS; 4 groups x 16 lanes consume 2 quads at a time (two
// 16B gathers in flight); denom accumulated unnormalized; one divide at end.
// At the measured ~78G line-req/s ceiling this is 4 lines/edge = minimum.
__global__ __launch_bounds__(256) void attn_row_kernel(
    const float* __restrict__ adj, const int* __restrict__ ecol,
    const float* __restrict__ sa1, const float* __restrict__ sa2,
    const int* __restrict__ row_ptr, const unsigned short* __restrict__ value,
    const float* __restrict__ bias, float* __restrict__ out, int N) {
  __shared__ float2 stash[4][64];
  int w = threadIdx.x >> 6;
  int lane = threadIdx.x & 63;
  int r = blockIdx.x * 4 + w;
  if (r >= N) return;
  int s = row_ptr[r], e = row_ptr[r + 1];
  float sa1r = sa1[r];
  int g = lane >> 4;    // edge-slot within quad
  int lg = lane & 15;   // owns bf16 cols [lg*8, lg*8+8)

  // prefetch bias early — overlaps the whole gather loop
  size_t o = (size_t)r * D_DIM + lg * 8 + g * 4;
  float4 bv = make_float4(0.f, 0.f, 0.f, 0.f);
  if (g < 2) bv = *(const float4*)&bias[o];

  float acc0 = 0.f, acc1 = 0.f, acc2 = 0.f, acc3 = 0.f;
  float acc4 = 0.f, acc5 = 0.f, acc6 = 0.f, acc7 = 0.f;
  float l = 0.f;
  const unsigned short* vbase = value + lg * 8;

  for (int base = s; base < e; base += 64) {
    int idx = base + lane;
    float p = 0.f;
    int c = 0;
    if (idx < e) {
      int cc = ecol[idx];
      float a = adj[idx];
      float v = a * sa1r + a * sa2[cc];
      float sc = v >= 0.f ? v : LEAKY * v;
      p = __expf(sc);
      c = cc;
    }
    l += wave_sum(p);
    stash[w][lane] = make_float2(p, __int_as_float(c));
    int cn = e - base;
    if (cn > 64) cn = 64;
    int cn4 = (cn + 3) & ~3;  // padded slots: p=0, c=0 -> harmless x0
    for (int j = 0; j < cn4; j += 8) {
      float2 pa = stash[w][j + g];
      bool second = (j + 4 < cn4);
      float2 pb = second ? stash[w][j + 4 + g] : make_float2(0.f, 0.f);
      u32x4 va = *(const u32x4*)(vbase + (size_t)__float_as_int(pa.y) * D_DIM);
      u32x4 vb = *(const u32x4*)(vbase + (size_t)__float_as_int(pb.y) * D_DIM);
      float pja = pa.x, pjb = pb.x;
      acc0 += pja * __uint_as_float(va[0] << 16);
      acc1 += pja * __uint_as_float(va[0] & 0xffff0000u);
      acc2 += pja * __uint_as_float(va[1] << 16);
      acc3 += pja * __uint_as_float(va[1] & 0xffff0000u);
      acc4 += pja * __uint_as_float(va[2] << 16);
      acc5 += pja * __uint_as_float(va[2] & 0xffff0000u);
      acc6 += pja * __uint_as_float(va[3] << 16);
      acc7 += pja * __uint_as_float(va[3] & 0xffff0000u);
      acc0 += pjb * __uint_as_float(vb[0] << 16);
      acc1 += pjb * __uint_as_float(vb[0] & 0xffff0000u);
      acc2 += pjb * __uint_as_float(vb[1] << 16);
      acc3 += pjb * __uint_as_float(vb[1] & 0xffff0000u);
      acc4 += pjb * __uint_as_float(vb[2] << 16);
      acc5 += pjb * __uint_as_float(vb[2] & 0xffff0000u);
      acc6 += pjb * __uint_as_float(vb[3] << 16);
      acc7 += pjb * __uint_as_float(vb[3] & 0xffff0000u);
    }
  }
  // combine the 4 edge-groups (lane bits 4,5)
  acc0 += __shfl_xor(acc0, 16); acc0 += __shfl_xor(acc0, 32);
  acc1 += __shfl_xor(acc1, 16); acc1 += __shfl_xor(acc1, 32);
  acc2 += __shfl_xor(acc2, 16); acc2 += __shfl_xor(acc2, 32);
  acc3 += __shfl_xor(acc3, 16); acc3 += __shfl_xor(acc3, 32);
  acc4 += __shfl_xor(acc4, 16); acc4 += __shfl_xor(acc4, 32);
  acc5 += __shfl_xor(acc5, 16); acc5 += __shfl_xor(acc5, 32);
  acc6 += __shfl_xor(acc6, 16); acc6 += __shfl_xor(acc6, 32);
  acc7 += __shfl_xor(acc7, 16); acc7 += __shfl_xor(acc7, 32);
  float invl = (l > 0.f) ? 1.f / l : 0.f;
  if (g < 2) {  // 32 lanes write 128 floats
    float4 ov;
    ov.x = bv.x + (g == 0 ? acc0 : acc4) * invl;
    ov.y = bv.y + (g == 0 ? acc1 : acc5) * invl;
    ov.z = bv.z + (g == 0 ? acc2 : acc6) * invl;
    ov.w = bv.w + (g == 0 ? acc3 : acc7) * invl;
    *(float4*)&out[o] = ov;
  }
}

extern "C" void kernel_launch(void* const* d_in, const int* in_sizes, int n_in,
                              void* d_out, int out_size, void* d_ws, size_t ws_size,
                              hipStream_t stream) {
  const float* x    = (const float*)d_in[0];
  const float* adj  = (const float*)d_in[1];
  const float* Wmap = (const float*)d_in[2];
  const float* w1   = (const float*)d_in[3];
  const float* b1   = (const float*)d_in[4];
  const float* w2   = (const float*)d_in[5];
  const float* b2   = (const float*)d_in[6];
  const float* kern = (const float*)d_in[7];
  const float* bias = (const float*)d_in[8];
  const int* erow   = (const int*)d_in[9];
  const int* ecol   = (const int*)d_in[10];
  float* out = (float*)d_out;

  int E = in_sizes[1];
  int D = in_sizes[3];          // 128
  int F = in_sizes[2] / D;      // 256
  int N = in_sizes[0] / F;      // 100000
  (void)D; (void)ws_size; (void)n_in; (void)out_size;

  char* ws = (char*)d_ws;
  size_t off = 0;
  float* u = (float*)(ws + off);          off += 2 * (size_t)F * sizeof(float);
  float* sa1 = (float*)(ws + off);        off += (size_t)N * sizeof(float);
  float* sa2 = (float*)(ws + off);        off += (size_t)N * sizeof(float);
  int* row_ptr = (int*)(ws + off);        off += (size_t)(N + 1) * sizeof(int);
  off = (off + 255) & ~(size_t)255;
  unsigned short* kTb = (unsigned short*)(ws + off);
  off += (size_t)F_DIM * D_DIM * sizeof(unsigned short);
  off = (off + 255) & ~(size_t)255;
  unsigned short* value = (unsigned short*)(ws + off);
  off += (size_t)N * D_DIM * sizeof(unsigned short);

  int rp_blocks = (N + 1 + 255) / 256;
  prep_kernel<<<1 + D_DIM + rp_blocks, 256, 0, stream>>>(
      Wmap, w1, w2, u, kern, kTb, erow, row_ptr, N, E);
  value_sa_gemm_kernel<<<(N + 127) / 128, 512, 0, stream>>>(x, kTb, u, b1, b2,
                                                            value, sa1, sa2, N);
  attn_row_kernel<<<(N + 3) / 4, 256, 0, stream>>>(adj, ecol, sa1, sa2, row_ptr,
                                                   value, bias, out, N);
}

// Round 12
// 112.830 us; speedup vs baseline: 1.0716x; 1.0716x over previous
//
#include <hip/hip_runtime.h>
#include <math.h>

#define F_DIM 256
#define D_DIM 128
#define LEAKY 0.2f

using bf16x8 = __attribute__((ext_vector_type(8))) short;
using f32x4  = __attribute__((ext_vector_type(4))) float;
using u32x4  = __attribute__((ext_vector_type(4))) unsigned;

__device__ __forceinline__ float wave_sum(float v) {
#pragma unroll
  for (int o = 32; o; o >>= 1) v += __shfl_xor(v, o);
  return v;
}
// fp32 -> bf16 round-to-nearest-even (bit-exact RNE)
__device__ __forceinline__ unsigned short f2bf(float f) {
  unsigned u = __float_as_uint(f);
  u += 0x7fffu + ((u >> 16) & 1u);
  return (unsigned short)(u >> 16);
}
__device__ __forceinline__ unsigned cvt2(float lo, float hi) {
  return (unsigned)f2bf(lo) | ((unsigned)f2bf(hi) << 16);
}

// Fused prep: block 0 -> u1/u2 = Wmap^T {w1,w2}; blocks 1..128 -> kTb
// transpose (one d-row each); blocks 129+ -> row_ptr binary search.
__global__ __launch_bounds__(256) void prep_kernel(
    const float* __restrict__ Wmap, const float* __restrict__ w1,
    const float* __restrict__ w2, float* __restrict__ u,
    const float* __restrict__ kern, unsigned short* __restrict__ kTb,
    const int* __restrict__ edge_row, int* __restrict__ row_ptr,
    int N, int E) {
  int bid = blockIdx.x;
  int t = threadIdx.x;
  if (bid == 0) {
    __shared__ float w1s[D_DIM], w2s[D_DIM];
    if (t < D_DIM) { w1s[t] = w1[t]; w2s[t] = w2[t]; }
    __syncthreads();
    float a1 = 0.f, a2 = 0.f;
    const float* wp = Wmap + (size_t)t * D_DIM;
#pragma unroll 8
    for (int d = 0; d < D_DIM; ++d) {
      float wv = wp[d];
      a1 += wv * w1s[d];
      a2 += wv * w2s[d];
    }
    u[t] = a1;
    u[F_DIM + t] = a2;
  } else if (bid <= D_DIM) {
    int d = bid - 1;        // 0..127
    int k = t;              // 0..255
    kTb[d * F_DIM + k] = f2bf(kern[(size_t)k * D_DIM + d]);
  } else {
    int r = (bid - D_DIM - 1) * 256 + t;
    if (r > N) return;
    int lo = 0, hi = E;
    while (lo < hi) {
      int mid = (lo + hi) >> 1;
      if (edge_row[mid] < r) lo = mid + 1; else hi = mid;
    }
    row_ptr[r] = lo;
  }
}

// Fused: value = bf16(x @ kernel) via MFMA (row-major [N][128]) +
// sa1/sa2 = x·u + b. Block = 4 waves, 64 rows. kTb (64 KB) staged in LDS
// once per block with XOR swizzle (write & read use the same involution).
// A-frag lane l: row (l&15), kg=(l>>4).
// C/D: col = l&15, row = (l>>4)*4 + i   [guide §3, m89-verified]
// NOTE: 256-thread/64-row config is the measured optimum — the 512-thread
// variant regressed (VGPR footprint broke 2-blocks/CU co-residency, R11).
__global__ __launch_bounds__(256) void value_sa_gemm_kernel(
    const float* __restrict__ x, const unsigned short* __restrict__ kTb,
    const float* __restrict__ u, const float* __restrict__ b1,
    const float* __restrict__ b2, unsigned short* __restrict__ value,
    float* __restrict__ sa1, float* __restrict__ sa2, int N) {
  __shared__ unsigned short ldsb[F_DIM * D_DIM];  // 64 KB exactly
  int tid = threadIdx.x;
  int w = tid >> 6, l = tid & 63;
  int rl = l & 15, kg = l >> 4;
  int row = blockIdx.x * 64 + w * 16 + rl;
  bool valid = row < N;
  int rowc = valid ? row : N - 1;

  bf16x8 stg[16];
#pragma unroll
  for (int it = 0; it < 16; ++it)
    stg[it] = *(const bf16x8*)(kTb + (size_t)(tid + it * 256) * 8);

  const float* xp = x + (size_t)rowc * F_DIM + kg * 8;
  float4 fxa[8], fxb[8];
#pragma unroll
  for (int ks = 0; ks < 8; ++ks) {
    fxa[ks] = *(const float4*)(xp + ks * 32);
    fxb[ks] = *(const float4*)(xp + ks * 32 + 4);
  }

#pragma unroll
  for (int it = 0; it < 16; ++it) {
    int c = tid + it * 256;
    int d = c >> 5;
    int sw = d * 512 + (((c & 31) * 16) ^ ((d & 7) << 4));
    *(bf16x8*)((char*)ldsb + sw) = stg[it];
  }

  const float* u1p = u + kg * 8;
  const float* u2p = u + F_DIM + kg * 8;
  float d1 = 0.f, d2 = 0.f;
  bf16x8 af[8];
#pragma unroll
  for (int ks = 0; ks < 8; ++ks) {
    float4 fa = fxa[ks], fb = fxb[ks];
    float4 ua = *(const float4*)(u1p + ks * 32);
    float4 ub = *(const float4*)(u1p + ks * 32 + 4);
    d1 += fa.x * ua.x + fa.y * ua.y + fa.z * ua.z + fa.w * ua.w +
          fb.x * ub.x + fb.y * ub.y + fb.z * ub.z + fb.w * ub.w;
    float4 va = *(const float4*)(u2p + ks * 32);
    float4 vb = *(const float4*)(u2p + ks * 32 + 4);
    d2 += fa.x * va.x + fa.y * va.y + fa.z * va.z + fa.w * va.w +
          fb.x * vb.x + fb.y * vb.y + fb.z * vb.z + fb.w * vb.w;
    u32x4 p;
    p[0] = cvt2(fa.x, fa.y);
    p[1] = cvt2(fa.z, fa.w);
    p[2] = cvt2(fb.x, fb.y);
    p[3] = cvt2(fb.z, fb.w);
    af[ks] = __builtin_bit_cast(bf16x8, p);
  }
  __syncthreads();

  f32x4 acc[8];
#pragma unroll
  for (int n = 0; n < 8; ++n) acc[n] = (f32x4){0.f, 0.f, 0.f, 0.f};
#pragma unroll
  for (int ks = 0; ks < 8; ++ks) {
    int bir = (ks * 64 + kg * 16) ^ ((rl & 7) << 4);
    const char* bp = (const char*)ldsb + rl * 512 + bir;
#pragma unroll
    for (int n = 0; n < 8; ++n) {
      bf16x8 b = *(const bf16x8*)(bp + n * 8192);
      acc[n] = __builtin_amdgcn_mfma_f32_16x16x32_bf16(af[ks], b, acc[n], 0, 0, 0);
    }
  }

  d1 += __shfl_xor(d1, 16); d1 += __shfl_xor(d1, 32);
  d2 += __shfl_xor(d2, 16); d2 += __shfl_xor(d2, 32);
  if (valid && kg == 0) {
    sa1[row] = d1 + b1[0];
    sa2[row] = d2 + b2[0];
  }
  int orow0 = blockIdx.x * 64 + w * 16 + kg * 4;
#pragma unroll
  for (int n = 0; n < 8; ++n) {
#pragma unroll
    for (int i = 0; i < 4; ++i) {
      int gr = orow0 + i;
      if (gr < N) value[(size_t)gr * D_DIM + n * 16 + rl] = f2bf(acc[n][i]);
    }
  }
}

// One wave per row, single pass, fixed softmax max = 0 (scores hard-bounded
// small by Cauchy-Schwarz; exp cannot overflow — identical to max-sub
// softmax). Per 64-edge chunk: lanes compute p=exp(sc) in parallel, stash
// (p, col) in LDS; 4 groups x 16 lanes consume 2 quads at a time (two
// 16B gathers in flight); denom accumulated unnormalized; one divide at end.
// At the measured ~78G line-req/s ceiling this is 4 lines/edge = minimum.
__global__ __launch_bounds__(256) void attn_row_kernel(
    const float* __restrict__ adj, const int* __restrict__ ecol,
    const float* __restrict__ sa1, const float* __restrict__ sa2,
    const int* __restrict__ row_ptr, const unsigned short* __restrict__ value,
    const float* __restrict__ bias, float* __restrict__ out, int N) {
  __shared__ float2 stash[4][64];
  int w = threadIdx.x >> 6;
  int lane = threadIdx.x & 63;
  int r = blockIdx.x * 4 + w;
  if (r >= N) return;
  int s = row_ptr[r], e = row_ptr[r + 1];
  float sa1r = sa1[r];
  int g = lane >> 4;    // edge-slot within quad
  int lg = lane & 15;   // owns bf16 cols [lg*8, lg*8+8)

  // prefetch bias early — overlaps the whole gather loop
  size_t o = (size_t)r * D_DIM + lg * 8 + g * 4;
  float4 bv = make_float4(0.f, 0.f, 0.f, 0.f);
  if (g < 2) bv = *(const float4*)&bias[o];

  float acc0 = 0.f, acc1 = 0.f, acc2 = 0.f, acc3 = 0.f;
  float acc4 = 0.f, acc5 = 0.f, acc6 = 0.f, acc7 = 0.f;
  float l = 0.f;
  const unsigned short* vbase = value + lg * 8;

  for (int base = s; base < e; base += 64) {
    int idx = base + lane;
    float p = 0.f;
    int c = 0;
    if (idx < e) {
      int cc = ecol[idx];
      float a = adj[idx];
      float v = a * sa1r + a * sa2[cc];
      float sc = v >= 0.f ? v : LEAKY * v;
      p = __expf(sc);
      c = cc;
    }
    l += wave_sum(p);
    stash[w][lane] = make_float2(p, __int_as_float(c));
    int cn = e - base;
    if (cn > 64) cn = 64;
    int cn4 = (cn + 3) & ~3;  // padded slots: p=0, c=0 -> harmless x0
    for (int j = 0; j < cn4; j += 8) {
      float2 pa = stash[w][j + g];
      bool second = (j + 4 < cn4);
      float2 pb = second ? stash[w][j + 4 + g] : make_float2(0.f, 0.f);
      u32x4 va = *(const u32x4*)(vbase + (size_t)__float_as_int(pa.y) * D_DIM);
      u32x4 vb = *(const u32x4*)(vbase + (size_t)__float_as_int(pb.y) * D_DIM);
      float pja = pa.x, pjb = pb.x;
      acc0 += pja * __uint_as_float(va[0] << 16);
      acc1 += pja * __uint_as_float(va[0] & 0xffff0000u);
      acc2 += pja * __uint_as_float(va[1] << 16);
      acc3 += pja * __uint_as_float(va[1] & 0xffff0000u);
      acc4 += pja * __uint_as_float(va[2] << 16);
      acc5 += pja * __uint_as_float(va[2] & 0xffff0000u);
      acc6 += pja * __uint_as_float(va[3] << 16);
      acc7 += pja * __uint_as_float(va[3] & 0xffff0000u);
      acc0 += pjb * __uint_as_float(vb[0] << 16);
      acc1 += pjb * __uint_as_float(vb[0] & 0xffff0000u);
      acc2 += pjb * __uint_as_float(vb[1] << 16);
      acc3 += pjb * __uint_as_float(vb[1] & 0xffff0000u);
      acc4 += pjb * __uint_as_float(vb[2] << 16);
      acc5 += pjb * __uint_as_float(vb[2] & 0xffff0000u);
      acc6 += pjb * __uint_as_float(vb[3] << 16);
      acc7 += pjb * __uint_as_float(vb[3] & 0xffff0000u);
    }
  }
  // combine the 4 edge-groups (lane bits 4,5)
  acc0 += __shfl_xor(acc0, 16); acc0 += __shfl_xor(acc0, 32);
  acc1 += __shfl_xor(acc1, 16); acc1 += __shfl_xor(acc1, 32);
  acc2 += __shfl_xor(acc2, 16); acc2 += __shfl_xor(acc2, 32);
  acc3 += __shfl_xor(acc3, 16); acc3 += __shfl_xor(acc3, 32);
  acc4 += __shfl_xor(acc4, 16); acc4 += __shfl_xor(acc4, 32);
  acc5 += __shfl_xor(acc5, 16); acc5 += __shfl_xor(acc5, 32);
  acc6 += __shfl_xor(acc6, 16); acc6 += __shfl_xor(acc6, 32);
  acc7 += __shfl_xor(acc7, 16); acc7 += __shfl_xor(acc7, 32);
  float invl = (l > 0.f) ? 1.f / l : 0.f;
  if (g < 2) {  // 32 lanes write 128 floats
    float4 ov;
    ov.x = bv.x + (g == 0 ? acc0 : acc4) * invl;
    ov.y = bv.y + (g == 0 ? acc1 : acc5) * invl;
    ov.z = bv.z + (g == 0 ? acc2 : acc6) * invl;
    ov.w = bv.w + (g == 0 ? acc3 : acc7) * invl;
    *(float4*)&out[o] = ov;
  }
}

extern "C" void kernel_launch(void* const* d_in, const int* in_sizes, int n_in,
                              void* d_out, int out_size, void* d_ws, size_t ws_size,
                              hipStream_t stream) {
  const float* x    = (const float*)d_in[0];
  const float* adj  = (const float*)d_in[1];
  const float* Wmap = (const float*)d_in[2];
  const float* w1   = (const float*)d_in[3];
  const float* b1   = (const float*)d_in[4];
  const float* w2   = (const float*)d_in[5];
  const float* b2   = (const float*)d_in[6];
  const float* kern = (const float*)d_in[7];
  const float* bias = (const float*)d_in[8];
  const int* erow   = (const int*)d_in[9];
  const int* ecol   = (const int*)d_in[10];
  float* out = (float*)d_out;

  int E = in_sizes[1];
  int D = in_sizes[3];          // 128
  int F = in_sizes[2] / D;      // 256
  int N = in_sizes[0] / F;      // 100000
  (void)D; (void)ws_size; (void)n_in; (void)out_size;

  char* ws = (char*)d_ws;
  size_t off = 0;
  float* u = (float*)(ws + off);          off += 2 * (size_t)F * sizeof(float);
  float* sa1 = (float*)(ws + off);        off += (size_t)N * sizeof(float);
  float* sa2 = (float*)(ws + off);        off += (size_t)N * sizeof(float);
  int* row_ptr = (int*)(ws + off);        off += (size_t)(N + 1) * sizeof(int);
  off = (off + 255) & ~(size_t)255;
  unsigned short* kTb = (unsigned short*)(ws + off);
  off += (size_t)F_DIM * D_DIM * sizeof(unsigned short);
  off = (off + 255) & ~(size_t)255;
  unsigned short* value = (unsigned short*)(ws + off);
  off += (size_t)N * D_DIM * sizeof(unsigned short);

  int rp_blocks = (N + 1 + 255) / 256;
  prep_kernel<<<1 + D_DIM + rp_blocks, 256, 0, stream>>>(
      Wmap, w1, w2, u, kern, kTb, erow, row_ptr, N, E);
  value_sa_gemm_kernel<<<(N + 63) / 64, 256, 0, stream>>>(x, kTb, u, b1, b2,
                                                          value, sa1, sa2, N);
  attn_row_kernel<<<(N + 3) / 4, 256, 0, stream>>>(adj, ecol, sa1, sa2, row_ptr,
                                                   value, bias, out, N);
}